// Round 15
// baseline (469.941 us; speedup 1.0000x reference)
//
#include <hip/hip_runtime.h>
#include <hip/hip_bf16.h>

#define DIN 128
#define HID 32
#define EPS 1e-5f
#define BUCK 256          // nodes per bucket
#define BSH 8
#define CHKC 256          // edge chunks
#define SCAP 13000        // staged records per chunk (chunk=12500 for E=3.2M)
#define RCAP 12288        // staged esort entries per bucket (mean 8192, +45 sigma)
#define WSC 16384.0f      // 2^14 fixed-point scale for w sums
#define WSI 6.103515625e-5f  // 2^-14

typedef unsigned int u32;
typedef unsigned short u16;
typedef unsigned long long u64;

// extract bf16 half of a packed u32 (hi=0 -> low 16 bits = even channel) as float
__device__ __forceinline__ float bfx(u32 v, int hi) {
    return __uint_as_float(hi ? (v & 0xffff0000u) : (v << 16));
}

__device__ __forceinline__ u16 f2bf(float f) {
    __hip_bfloat16 h = __float2bfloat16(f);
    return *reinterpret_cast<u16*>(&h);
}

// ---------------- zero BN stats ----------------
__global__ void init_stats(float* __restrict__ stats) {
    if (threadIdx.x < 192) stats[threadIdx.x] = 0.f;
}

// ---------------- phase A: per-(chunk) LDS bucket histogram ----------------
__global__ __launch_bounds__(1024) void bucket_count(
        const int* __restrict__ col, int E, u32* __restrict__ cpart2, int nbuck) {
    __shared__ u32 cnt[512];
    int c = blockIdx.x;
    for (int i = threadIdx.x; i < 512; i += 1024) cnt[i] = 0;
    __syncthreads();
    int chunk = (E + CHKC - 1) / CHKC;
    int e0 = c * chunk, e1 = e0 + chunk;
    if (e1 > E) e1 = E;
    for (int e = e0 + threadIdx.x; e < e1; e += 1024)
        atomicAdd(&cnt[col[e] >> BSH], 1u);
    __syncthreads();
    for (int i = threadIdx.x; i < nbuck; i += 1024)
        cpart2[i * CHKC + c] = cnt[i];
}

// ---------------- exclusive scan (for the (bucket,chunk) cells) ----------------
__global__ void scan_blocks(int* __restrict__ data, int* __restrict__ bsum, int n) {
    __shared__ int s[256];
    int i = blockIdx.x * 256 + threadIdx.x;
    int v = (i < n) ? data[i] : 0;
    s[threadIdx.x] = v;
    __syncthreads();
    for (int off = 1; off < 256; off <<= 1) {
        int t = (threadIdx.x >= off) ? s[threadIdx.x - off] : 0;
        __syncthreads();
        s[threadIdx.x] += t;
        __syncthreads();
    }
    if (i < n) data[i] = s[threadIdx.x] - v;  // exclusive
    if (threadIdx.x == 255) bsum[blockIdx.x] = s[255];
}

__global__ void scan_tops(int* __restrict__ bsum, int nb) {
    __shared__ int s[512];
    int v = (threadIdx.x < nb) ? bsum[threadIdx.x] : 0;
    s[threadIdx.x] = v;
    __syncthreads();
    for (int off = 1; off < 512; off <<= 1) {
        int t = (threadIdx.x >= off) ? s[threadIdx.x - off] : 0;
        __syncthreads();
        s[threadIdx.x] += t;
        __syncthreads();
    }
    if (threadIdx.x < nb) bsum[threadIdx.x] = s[threadIdx.x] - v;  // exclusive
}

__global__ void scan_addback(int* __restrict__ data, const int* __restrict__ bsum,
                             int n, int E) {
    int i = blockIdx.x * 256 + threadIdx.x;
    if (i < n) data[i] += bsum[blockIdx.x];
    if (i == n) data[n] = E;  // sentinel
}

// ---------------- phase C: LDS counting-sort scatter (all global writes coalesced) --
// record u64 = w_bits<<32 | src<<BSH | col_in_bucket.
__global__ __launch_bounds__(1024) void bucket_scatter(
        const int* __restrict__ row, const int* __restrict__ col,
        const float* __restrict__ w, const u32* __restrict__ cpart2,
        u64* __restrict__ rec8, int E, int nbuck) {
    __shared__ u64 srec[SCAP];                    // 104KB
    __shared__ u32 lcnt[512], lbase[512], lcur[512], cellb[512];
    int c = blockIdx.x, tid = threadIdx.x;
    int chunk = (E + CHKC - 1) / CHKC;
    int e0 = c * chunk, e1 = e0 + chunk;
    if (e1 > E) e1 = E;
    for (int i = tid; i < 512; i += 1024) lcnt[i] = 0;
    __syncthreads();
    if (chunk <= SCAP) {
        for (int e = e0 + tid; e < e1; e += 1024)
            atomicAdd(&lcnt[col[e] >> BSH], 1u);
        __syncthreads();
        if (tid < 512) lbase[tid] = lcnt[tid];
        __syncthreads();
        for (int off = 1; off < 512; off <<= 1) {
            u32 t = 0;
            if (tid < 512 && tid >= off) t = lbase[tid - off];
            __syncthreads();
            if (tid < 512) lbase[tid] += t;
            __syncthreads();
        }
        if (tid < 512) {
            lcur[tid] = lbase[tid] - lcnt[tid];  // exclusive base
            cellb[tid] = (tid < nbuck) ? cpart2[tid * CHKC + c] : 0;
        }
        __syncthreads();
        for (int e = e0 + tid; e < e1; e += 1024) {
            int cc = col[e];
            int b = cc >> BSH;
            u32 p = atomicAdd(&lcur[b], 1u);
            srec[p] = ((u64)__float_as_uint(w[e]) << 32) |
                      ((u64)(u32)row[e] << BSH) | (u64)(u32)(cc & (BUCK - 1));
        }
        __syncthreads();
        int wv = tid >> 6, lane = tid & 63;
        for (int b = wv; b < nbuck; b += 16) {
            int len = (int)lcnt[b];
            int s = (int)(lbase[b] - lcnt[b]);
            u64* dst = rec8 + cellb[b];
            for (int j = lane; j < len; j += 64) dst[j] = srec[s + j];
        }
    } else {
        if (tid < 512) lcur[tid] = (tid < nbuck) ? cpart2[tid * CHKC + c] : 0;
        __syncthreads();
        for (int e = e0 + tid; e < e1; e += 1024) {
            int cc = col[e];
            int b = cc >> BSH;
            u32 pos = atomicAdd(&lcur[b], 1u);
            rec8[pos] = ((u64)__float_as_uint(w[e]) << 32) |
                        ((u64)(u32)row[e] << BSH) | (u64)(u32)(cc & (BUCK - 1));
        }
    }
}

// ---------------- phase D+F fused: hist -> rowptr/dinv -> rank -> esort ----------------
// Entry stores bf16(w * dinv[dst]) (dst local -> no cross-bucket read; R12 fix).
__global__ __launch_bounds__(1024) void bucket_finalize(
        const u64* __restrict__ rec8, const u32* __restrict__ cpart2,
        int* __restrict__ rowptr, int* __restrict__ midptr,
        float* __restrict__ dinv, u32* __restrict__ esort,
        int E, int N, int nbuck, int H) {
    __shared__ u32 stage[RCAP];   // 48KB
    __shared__ u64 cw[BUCK];      // 2KB
    __shared__ int sp[BUCK];
    __shared__ u32 cA[BUCK];      // count of src<H per dst
    __shared__ u32 cntA[BUCK], cntB[BUCK];
    __shared__ float dl[BUCK];
    __shared__ int baseA[BUCK], baseB[BUCK];
    int b = blockIdx.x, tid = threadIdx.x;
    int k0 = (int)cpart2[b * CHKC];
    int k1 = (b + 1 < nbuck) ? (int)cpart2[(b + 1) * CHKC] : E;
    for (int i = tid; i < BUCK; i += 1024) { cw[i] = 0ull; cA[i] = 0; }
    __syncthreads();
    for (int k = k0 + tid; k < k1; k += 1024) {
        u64 v = rec8[k];
        u32 lo = (u32)v;
        int i = (int)(lo & (BUCK - 1));
        int src = (int)(lo >> BSH);
        float wv = __uint_as_float((u32)(v >> 32));
        atomicAdd(&cw[i], (1ull << 32) | (u64)(u32)(wv * WSC + 0.5f));
        if (src < H) atomicAdd(&cA[i], 1u);
    }
    __syncthreads();
    if (tid < BUCK) sp[tid] = (int)(cw[tid] >> 32);
    __syncthreads();
    for (int off = 1; off < BUCK; off <<= 1) {
        int t = 0;
        if (tid < BUCK && tid >= off) t = sp[tid - off];
        __syncthreads();
        if (tid < BUCK) sp[tid] += t;
        __syncthreads();
    }
    if (tid < BUCK) {
        int g = (b << BSH) + tid;
        int own = (int)(cw[tid] >> 32);
        float dv = rsqrtf(1.0f + (float)(u32)cw[tid] * WSI);  // +1 self loop
        int bA = sp[tid] - own;
        cntA[tid] = 0;
        cntB[tid] = 0;
        baseA[tid] = bA;
        baseB[tid] = bA + (int)cA[tid];
        dl[tid] = dv;
        if (g < N) {
            rowptr[g] = k0 + bA;
            midptr[g] = k0 + bA + (int)cA[tid];
            dinv[g] = dv;
        }
    }
    if (b == nbuck - 1 && tid == 0) rowptr[N] = E;
    __syncthreads();
    for (int k = k0 + tid; k < k1; k += 1024) {
        u64 v = rec8[k];  // L2-hot re-read
        u32 lo = (u32)v;
        int i = (int)(lo & (BUCK - 1));
        int src = (int)(lo >> BSH);
        float nv = __uint_as_float((u32)(v >> 32)) * dl[i];  // w * dinv[dst]
        u32 entry = ((u32)src << 15) | (u32)f2bf(nv);
        int off;
        if (src < H) off = baseA[i] + (int)atomicAdd(&cntA[i], 1u);
        else         off = baseB[i] + (int)atomicAdd(&cntB[i], 1u);
        if (off < RCAP) stage[off] = entry;
        else esort[k0 + off] = entry;  // overflow guard (statistically unreachable)
    }
    __syncthreads();
    int len = k1 - k0;
    int lim = len < RCAP ? len : RCAP;
    for (int j = tid; j < lim; j += 1024) esort[k0 + j] = stage[j];
}

// ---------------- layer-0 GEMM v3: 4-node register blocking ----------------
// Thread = 4 nodes x 4 ch (acc[4][4]); per 4 k-steps: 4 x-b128 + 4 W-b128 = 96
// LDS-cyc for 64 VALU-cyc of FMA (was 18 LDS per 8 VALU -> 3.6x less LDS/FMA).
// Block = 128 nodes; x staged per-thread half-row (t&127 mapping) to keep LDS
// stage-write conflicts <=8-way. hbf = dinv[node] * (x@W), node-major bf16.
__global__ __launch_bounds__(256) void gemm_din(const float* __restrict__ x,
                                                const float* __restrict__ W,
                                                const float* __restrict__ dinv,
                                                u16* __restrict__ hbf, int n) {
    __shared__ float xl[128][132];   // 67.6KB
    __shared__ float Wl[DIN * HID];  // 16KB, k-major
    int t = threadIdx.x;
    for (int i = t; i < DIN * HID; i += 256) Wl[i] = W[i];
    int nbase = blockIdx.x * 128;
    int nrows = n - nbase; if (nrows > 128) nrows = 128;
    {
        int nn = t & 127;
        int q0 = t >> 7;  // 0 or 1: even/odd quads of the row
        if (nn < nrows) {
            const float* xr = x + (size_t)(nbase + nn) * DIN;
#pragma unroll
            for (int q = 0; q < 16; ++q) {
                int qq = q0 + 2 * q;
                *(float4*)&xl[nn][qq * 4] = *(const float4*)&xr[qq * 4];
            }
        }
    }
    __syncthreads();
    int chq = t & 7, nq = t >> 3;  // nq 0..31 -> nodes 4nq..4nq+3
    int n0 = 4 * nq;
    if (n0 >= nrows) return;
    float acc[4][4] = {};
    for (int k4 = 0; k4 < DIN; k4 += 4) {
        float4 xv[4];
        xv[0] = *(float4*)&xl[n0][k4];
        xv[1] = *(float4*)&xl[n0 + 1][k4];
        xv[2] = *(float4*)&xl[n0 + 2][k4];
        xv[3] = *(float4*)&xl[n0 + 3][k4];
#pragma unroll
        for (int j = 0; j < 4; ++j) {
            float4 wv = *(float4*)&Wl[(k4 + j) * HID + chq * 4];
#pragma unroll
            for (int r = 0; r < 4; ++r) {
                float f = ((const float*)&xv[r])[j];
                acc[r][0] += f * wv.x;
                acc[r][1] += f * wv.y;
                acc[r][2] += f * wv.z;
                acc[r][3] += f * wv.w;
            }
        }
    }
    int ch0 = chq * 4;
#pragma unroll
    for (int r = 0; r < 4; ++r) {
        if (n0 + r < nrows) {
            int node = nbase + n0 + r;
            float dv = dinv[node];
            u64 pk = (u64)f2bf(acc[r][0] * dv) | ((u64)f2bf(acc[r][1] * dv) << 16) |
                     ((u64)f2bf(acc[r][2] * dv) << 32) | ((u64)f2bf(acc[r][3] * dv) << 48);
            *(u64*)&hbf[(size_t)node * 32 + ch0] = pk;
        }
    }
}

// ---------------- hidden GEMM v3: BN+ReLU applied at STAGE time, 4-node blocking ----
__global__ __launch_bounds__(256) void gemm_hid_bn(
        const float* __restrict__ aS, const float* __restrict__ W,
        const float* __restrict__ stats, const float* __restrict__ g,
        const float* __restrict__ be, const float* __restrict__ dinv,
        u16* __restrict__ hbf, int n, float invN) {
    __shared__ float xl[128][36];    // 18.4KB, holds POST-BN-ReLU activations
    __shared__ float Wl[HID * HID];  // 4KB, k-major
    __shared__ float sc[HID], sh[HID];
    int t = threadIdx.x;
    for (int i = t; i < HID * HID; i += 256) Wl[i] = W[i];
    if (t < HID) {
        float mu = stats[t] * invN;
        float var = stats[32 + t] * invN - mu * mu;
        float s = rsqrtf(var + EPS) * g[t];
        sc[t] = s;
        sh[t] = be[t] - mu * s;
    }
    __syncthreads();  // sc/sh ready for the BN-at-stage pass
    int nbase = blockIdx.x * 128;
    int nrows = n - nbase; if (nrows > 128) nrows = 128;
    for (int i = t; i < nrows * 8; i += 256) {
        int nn = i >> 3, q = i & 7;
        float4 v = *(const float4*)&aS[(size_t)(nbase + nn) * 32 + q * 4];
        float4 s4 = *(const float4*)&sc[q * 4];
        float4 h4 = *(const float4*)&sh[q * 4];
        v.x = fmaxf(v.x * s4.x + h4.x, 0.f);
        v.y = fmaxf(v.y * s4.y + h4.y, 0.f);
        v.z = fmaxf(v.z * s4.z + h4.z, 0.f);
        v.w = fmaxf(v.w * s4.w + h4.w, 0.f);
        *(float4*)&xl[nn][q * 4] = v;
    }
    __syncthreads();
    int chq = t & 7, nq = t >> 3;
    int n0 = 4 * nq;
    if (n0 >= nrows) return;
    float acc[4][4] = {};
    for (int k4 = 0; k4 < HID; k4 += 4) {
        float4 xv[4];
        xv[0] = *(float4*)&xl[n0][k4];
        xv[1] = *(float4*)&xl[n0 + 1][k4];
        xv[2] = *(float4*)&xl[n0 + 2][k4];
        xv[3] = *(float4*)&xl[n0 + 3][k4];
#pragma unroll
        for (int j = 0; j < 4; ++j) {
            float4 wv = *(float4*)&Wl[(k4 + j) * HID + chq * 4];
#pragma unroll
            for (int r = 0; r < 4; ++r) {
                float f = ((const float*)&xv[r])[j];
                acc[r][0] += f * wv.x;
                acc[r][1] += f * wv.y;
                acc[r][2] += f * wv.z;
                acc[r][3] += f * wv.w;
            }
        }
    }
    int ch0 = chq * 4;
#pragma unroll
    for (int r = 0; r < 4; ++r) {
        if (n0 + r < nrows) {
            int node = nbase + n0 + r;
            float dv = dinv[node];
            u64 pk = (u64)f2bf(acc[r][0] * dv) | ((u64)f2bf(acc[r][1] * dv) << 16) |
                     ((u64)f2bf(acc[r][2] * dv) << 32) | ((u64)f2bf(acc[r][3] * dv) << 48);
            *(u64*)&hbf[(size_t)node * 32 + ch0] = pk;
        }
    }
}

// ---------------- single-pass CSR gather, v4: 8-deep batched loads ----------------
// 8 lanes/node (uint2/edge). Row loop batches 8 edges: load 8 contiguous esort
// entries into regs, then issue all 8 independent h2 loads together.
template<int RELU>
__global__ __launch_bounds__(256) void gather_t(
        const u32* __restrict__ h2, const int* __restrict__ rowptr,
        const u32* __restrict__ esort, const float* __restrict__ dinv,
        const float* __restrict__ b, float* __restrict__ out, int n) {
    int q = threadIdx.x & 7;
    int node = blockIdx.x * 32 + (threadIdx.x >> 3);
    if (node >= n) return;
    float s = dinv[node];   // hbf already carries one dinv factor
    uint2 hv = *(const uint2*)&h2[(size_t)node * 16 + q * 2];
    float acc[4];
    acc[0] = s * bfx(hv.x, 0) + b[q * 4 + 0];
    acc[1] = s * bfx(hv.x, 1) + b[q * 4 + 1];
    acc[2] = s * bfx(hv.y, 0) + b[q * 4 + 2];
    acc[3] = s * bfx(hv.y, 1) + b[q * 4 + 3];
    int j = rowptr[node], end = rowptr[node + 1];
    for (; j + 8 <= end; j += 8) {
        u32 em[8];
#pragma unroll
        for (int u = 0; u < 8; ++u) em[u] = esort[j + u];
        uint2 v[8];
#pragma unroll
        for (int u = 0; u < 8; ++u)
            v[u] = *(const uint2*)&h2[(size_t)(em[u] >> 15) * 16 + q * 2];
#pragma unroll
        for (int u = 0; u < 8; ++u) {
            float nv = __uint_as_float((em[u] & 0x7fffu) << 16);
            acc[0] += nv * bfx(v[u].x, 0);
            acc[1] += nv * bfx(v[u].x, 1);
            acc[2] += nv * bfx(v[u].y, 0);
            acc[3] += nv * bfx(v[u].y, 1);
        }
    }
    if (j + 4 <= end) {
        u32 em[4];
#pragma unroll
        for (int u = 0; u < 4; ++u) em[u] = esort[j + u];
        uint2 v[4];
#pragma unroll
        for (int u = 0; u < 4; ++u)
            v[u] = *(const uint2*)&h2[(size_t)(em[u] >> 15) * 16 + q * 2];
#pragma unroll
        for (int u = 0; u < 4; ++u) {
            float nv = __uint_as_float((em[u] & 0x7fffu) << 16);
            acc[0] += nv * bfx(v[u].x, 0);
            acc[1] += nv * bfx(v[u].x, 1);
            acc[2] += nv * bfx(v[u].y, 0);
            acc[3] += nv * bfx(v[u].y, 1);
        }
        j += 4;
    }
    for (; j < end; ++j) {
        u32 ed = esort[j];
        uint2 v = *(const uint2*)&h2[(size_t)(ed >> 15) * 16 + q * 2];
        float nv = __uint_as_float((ed & 0x7fffu) << 16);
        acc[0] += nv * bfx(v.x, 0);
        acc[1] += nv * bfx(v.x, 1);
        acc[2] += nv * bfx(v.y, 0);
        acc[3] += nv * bfx(v.y, 1);
    }
    if (RELU) {
#pragma unroll
        for (int i = 0; i < 4; ++i) acc[i] = fmaxf(acc[i], 0.f);
    }
    float4 o = {acc[0], acc[1], acc[2], acc[3]};
    *(float4*)&out[(size_t)node * 32 + q * 4] = o;
}

// ---------------- BN stats reduce (node-major agg) ----------------
__global__ void bn_reduce(const float* __restrict__ aS, float* __restrict__ stats, int n) {
    __shared__ float s1[256], s2[256];
    int ch = threadIdx.x & 31, rg = threadIdx.x >> 5;
    float a = 0.f, b = 0.f;
    for (int node = blockIdx.x * 8 + rg; node < n; node += gridDim.x * 8) {
        float v = aS[(size_t)node * 32 + ch];
        a += v;
        b += v * v;
    }
    s1[threadIdx.x] = a;
    s2[threadIdx.x] = b;
    __syncthreads();
    if (threadIdx.x < 32) {
        float ta = 0.f, tb = 0.f;
#pragma unroll
        for (int j = 0; j < 8; ++j) {
            ta += s1[j * 32 + threadIdx.x];
            tb += s2[j * 32 + threadIdx.x];
        }
        atomicAdd(&stats[threadIdx.x], ta);
        atomicAdd(&stats[32 + threadIdx.x], tb);
    }
}

extern "C" void kernel_launch(void* const* d_in, const int* in_sizes, int n_in,
                              void* d_out, int out_size, void* d_ws, size_t ws_size,
                              hipStream_t stream) {
    const int N = in_sizes[0] / DIN;
    const int E = in_sizes[2];
    const int nbuck = (N + BUCK - 1) >> BSH;  // 391 for N=100000
    const int nb256 = nbuck * CHKC;           // 100096 cells
    const int H = N / 2;

    const float* x = (const float*)d_in[0];
    const int* ei = (const int*)d_in[1];
    const float* ew = (const float*)d_in[2];
    const int* row = ei;
    const int* col = ei + E;

    const float* Ws[4] = {(const float*)d_in[3], (const float*)d_in[5],
                          (const float*)d_in[7], (const float*)d_in[9]};
    const float* bs[4] = {(const float*)d_in[4], (const float*)d_in[6],
                          (const float*)d_in[8], (const float*)d_in[10]};
    const float* gs[3] = {(const float*)d_in[11], (const float*)d_in[13], (const float*)d_in[15]};
    const float* bes[3] = {(const float*)d_in[12], (const float*)d_in[14], (const float*)d_in[16]};

    // workspace layout, every buffer 256B-aligned (~41 MB total)
    char* wsb = (char*)d_ws;
    size_t off0 = 0;
    auto alloc = [&](size_t bytes) -> void* {
        off0 = (off0 + 255) & ~(size_t)255;
        void* p = wsb + off0;
        off0 += bytes;
        return p;
    };
    float* dinv = (float*)alloc((size_t)N * 4);
    int* rowptr = (int*)alloc((size_t)(N + 1) * 4);
    int* midptr = (int*)alloc((size_t)N * 4);
    u32* esort = (u32*)alloc((size_t)E * 4);
    float* stats = (float*)alloc(192 * 4);
    int* bsum = (int*)alloc(512 * 4);
    u32* cpart2 = (u32*)alloc((size_t)(nb256 + 256) * 4);
    // RR region: hbf (6.4M, node-major) + aggS (12.8M, node-major); rec8 (E*8=25.6M)
    // aliases it — rec8 dead before gemm_din first writes hbf.
    size_t rrMin = (size_t)N * HID * 6;
    size_t rrBytes = (size_t)E * 8 > rrMin ? (size_t)E * 8 : rrMin;
    char* RR = (char*)alloc(rrBytes);
    u16* hbf = (u16*)RR;
    float* aggS = (float*)(RR + (size_t)N * HID * 2);
    u64* rec8 = (u64*)RR;

    const int B = 256;
    const int nodeGrid32 = (N + 31) / 32;    // 3125 blocks (gather)
    const int nodeGrid128 = (N + 127) / 128; // 782 blocks (gemms)
    const int scanB = (nb256 + 255) / 256;   // 392 <= 512
    const float invN = 1.0f / (float)N;

    // ---- build CSR + norm: LDS counting sort, all global writes coalesced ----
    init_stats<<<1, 256, 0, stream>>>(stats);
    bucket_count<<<CHKC, 1024, 0, stream>>>(col, E, cpart2, nbuck);
    scan_blocks<<<scanB, 256, 0, stream>>>((int*)cpart2, bsum, nb256);
    scan_tops<<<1, 512, 0, stream>>>(bsum, scanB);
    scan_addback<<<scanB + 1, 256, 0, stream>>>((int*)cpart2, bsum, nb256, E);
    bucket_scatter<<<CHKC, 1024, 0, stream>>>(row, col, ew, cpart2, rec8, E, nbuck);
    bucket_finalize<<<nbuck, 1024, 0, stream>>>(rec8, cpart2, rowptr, midptr, dinv,
                                                esort, E, N, nbuck, H);
    gemm_din<<<nodeGrid128, 256, 0, stream>>>(x, Ws[0], dinv, hbf, N);  // rec8 now dead

    // ---- layers: gemm (l>0) -> single-pass deep-MLP gather -> bn_reduce ----
    for (int l = 0; l < 4; ++l) {
        if (l > 0)
            gemm_hid_bn<<<nodeGrid128, 256, 0, stream>>>(aggS, Ws[l], stats + 64 * (l - 1),
                                                         gs[l - 1], bes[l - 1], dinv,
                                                         hbf, N, invN);
        if (l < 3) {
            gather_t<0><<<nodeGrid32, B, 0, stream>>>((const u32*)hbf, rowptr, esort,
                                                      dinv, bs[l], aggS, N);
            bn_reduce<<<512, B, 0, stream>>>(aggS, stats + 64 * l, N);
        } else {
            // final layer: gather + ReLU straight to d_out
            gather_t<1><<<nodeGrid32, B, 0, stream>>>((const u32*)hbf, rowptr, esort,
                                                      dinv, bs[l], (float*)d_out, N);
        }
    }
}